// Round 1
// baseline (43.736 us; speedup 1.0000x reference)
//
#include <hip/hip_runtime.h>
#include <hip/hip_bf16.h>
#include <math.h>

// out[i,j] = max( (x[i]·W[j]) / (|x_i| |W_j|), 1e-10 ) + b[j]
// B=65536, IN=OUT=256, fp32 in/out. bf16 MFMA, W fully LDS-resident (swizzled).

using bf16x8 = __attribute__((ext_vector_type(8))) short;   // 8 bf16 = 4 VGPRs
using f32x4  = __attribute__((ext_vector_type(4))) float;   // MFMA accumulator

#define LDS_BYTES (131072 + 1024 + 1024)   // W bf16 swizzled + winv[256] + b[256]

__device__ __forceinline__ short f2bf(float f) {
    __bf16 h = (__bf16)f;                  // RNE; compiler fuses pairs to v_cvt_pk_bf16_f32
    return __builtin_bit_cast(short, h);
}

__global__ __launch_bounds__(512, 2) void ffn_cosnorm_kernel(
    const float* __restrict__ x, const float* __restrict__ W,
    const float* __restrict__ b, float* __restrict__ out)
{
    extern __shared__ char smem[];
    float* winv = (float*)(smem + 131072);   // [256] 1/|W_j|
    float* blds = (float*)(smem + 132096);   // [256] bias

    const int t = threadIdx.x;

    // ---------------- prologue: stage W (fp32 -> bf16, XOR-swizzled) + w_len ----------------
    {
        const int row  = t >> 1;            // 0..255 (W row = output col j)
        const int half = t & 1;             // which 128-col half
        const float* wr = W + row * 256 + half * 128;
        const int rx = (row & 7) << 4;      // swizzle term
        float ss = 0.f;
        #pragma unroll
        for (int i = 0; i < 16; ++i) {      // 16 groups of 8 floats
            float4 a = *(const float4*)(wr + i * 8);
            float4 c = *(const float4*)(wr + i * 8 + 4);
            ss = fmaf(a.x, a.x, ss); ss = fmaf(a.y, a.y, ss);
            ss = fmaf(a.z, a.z, ss); ss = fmaf(a.w, a.w, ss);
            ss = fmaf(c.x, c.x, ss); ss = fmaf(c.y, c.y, ss);
            ss = fmaf(c.z, c.z, ss); ss = fmaf(c.w, c.w, ss);
            bf16x8 v;
            v[0] = f2bf(a.x); v[1] = f2bf(a.y); v[2] = f2bf(a.z); v[3] = f2bf(a.w);
            v[4] = f2bf(c.x); v[5] = f2bf(c.y); v[6] = f2bf(c.z); v[7] = f2bf(c.w);
            const int off = row * 512 + ((half * 256 + i * 16) ^ rx);
            *(bf16x8*)(smem + off) = v;     // ds_write_b128, ~2-way (free)
        }
        ss += __shfl_xor(ss, 1);            // combine the two halves (adjacent lanes)
        if (!half) winv[row] = 1.0f / sqrtf(ss);
        if (t < 256) blds[t] = b[t];
    }
    __syncthreads();                        // only block-wide barrier

    // ---------------- main: each wave owns 32 rows (2 M-tiles of 16), all 256 cols ----------------
    const int lane = t & 63;
    const int wave = t >> 6;                // 0..7
    const int r16  = lane & 15;
    const int kg   = lane >> 4;             // 0..3 : K-group of 8
    const int rxor = (r16 & 7) << 4;        // B-frag read swizzle
    const size_t rowBase = (size_t)blockIdx.x * 256 + (size_t)wave * 32;

    const float* xp0 = x + (rowBase + r16) * 256 + kg * 8;   // M-tile 0 row
    const float* xp1 = xp0 + 16 * 256;                        // M-tile 1 row

    f32x4 acc0[16], acc1[16];
    #pragma unroll
    for (int n = 0; n < 16; ++n) {
        acc0[n] = f32x4{0.f, 0.f, 0.f, 0.f};
        acc1[n] = f32x4{0.f, 0.f, 0.f, 0.f};
    }

    float ss0 = 0.f, ss1 = 0.f;

    float4 c0a = *(const float4*)(xp0);
    float4 c0b = *(const float4*)(xp0 + 4);
    float4 c1a = *(const float4*)(xp1);
    float4 c1b = *(const float4*)(xp1 + 4);

    #pragma unroll
    for (int k0 = 0; k0 < 8; ++k0) {        // K = 8 steps of 32
        float4 n0a, n0b, n1a, n1b;
        if (k0 < 7) {                        // depth-1 prefetch of next K-step
            const float* p0 = xp0 + (k0 + 1) * 32;
            n0a = *(const float4*)(p0);  n0b = *(const float4*)(p0 + 4);
            const float* p1 = xp1 + (k0 + 1) * 32;
            n1a = *(const float4*)(p1);  n1b = *(const float4*)(p1 + 4);
        }
        // convert current to bf16 frags + accumulate sum of squares (fp32)
        bf16x8 a0, a1;
        a0[0] = f2bf(c0a.x); a0[1] = f2bf(c0a.y); a0[2] = f2bf(c0a.z); a0[3] = f2bf(c0a.w);
        a0[4] = f2bf(c0b.x); a0[5] = f2bf(c0b.y); a0[6] = f2bf(c0b.z); a0[7] = f2bf(c0b.w);
        a1[0] = f2bf(c1a.x); a1[1] = f2bf(c1a.y); a1[2] = f2bf(c1a.z); a1[3] = f2bf(c1a.w);
        a1[4] = f2bf(c1b.x); a1[5] = f2bf(c1b.y); a1[6] = f2bf(c1b.z); a1[7] = f2bf(c1b.w);
        ss0 = fmaf(c0a.x, c0a.x, ss0); ss0 = fmaf(c0a.y, c0a.y, ss0);
        ss0 = fmaf(c0a.z, c0a.z, ss0); ss0 = fmaf(c0a.w, c0a.w, ss0);
        ss0 = fmaf(c0b.x, c0b.x, ss0); ss0 = fmaf(c0b.y, c0b.y, ss0);
        ss0 = fmaf(c0b.z, c0b.z, ss0); ss0 = fmaf(c0b.w, c0b.w, ss0);
        ss1 = fmaf(c1a.x, c1a.x, ss1); ss1 = fmaf(c1a.y, c1a.y, ss1);
        ss1 = fmaf(c1a.z, c1a.z, ss1); ss1 = fmaf(c1a.w, c1a.w, ss1);
        ss1 = fmaf(c1b.x, c1b.x, ss1); ss1 = fmaf(c1b.y, c1b.y, ss1);
        ss1 = fmaf(c1b.z, c1b.z, ss1); ss1 = fmaf(c1b.w, c1b.w, ss1);

        const int cswz = (k0 * 64 + kg * 16) ^ rxor;   // swizzled byte-col in W row
        #pragma unroll
        for (int n = 0; n < 16; ++n) {
            const int addr = (n * 16 + r16) * 512 + cswz;
            bf16x8 bfr = *(const bf16x8*)(smem + addr);  // ds_read_b128, conflict-free
            acc0[n] = __builtin_amdgcn_mfma_f32_16x16x32_bf16(a0, bfr, acc0[n], 0, 0, 0);
            acc1[n] = __builtin_amdgcn_mfma_f32_16x16x32_bf16(a1, bfr, acc1[n], 0, 0, 0);
        }
        c0a = n0a; c0b = n0b; c1a = n1a; c1b = n1b;
    }

    // ---------------- x_len: butterfly over K-groups, redistribute via shfl ----------------
    ss0 += __shfl_xor(ss0, 16); ss0 += __shfl_xor(ss0, 32);   // now full row sumsq, row = r16
    ss1 += __shfl_xor(ss1, 16); ss1 += __shfl_xor(ss1, 32);
    const float inv0 = 1.0f / sqrtf(ss0);
    const float inv1 = 1.0f / sqrtf(ss1);

    // C layout (m89): col = lane&15, row = (lane>>4)*4 + reg. Lane needs x_len of rows kg*4+r.
    float xi0[4], xi1[4];
    #pragma unroll
    for (int r = 0; r < 4; ++r) {
        xi0[r] = __shfl(inv0, kg * 4 + r);
        xi1[r] = __shfl(inv1, kg * 4 + r);
    }

    // ---------------- epilogue: scale, clamp, +bias, store ----------------
    float* op = out + (rowBase + kg * 4) * 256 + r16;
    #pragma unroll
    for (int n = 0; n < 16; ++n) {
        const float wi = winv[n * 16 + r16];
        const float bb = blds[n * 16 + r16];
        #pragma unroll
        for (int r = 0; r < 4; ++r) {
            const float v0 = fmaxf(acc0[n][r] * (xi0[r] * wi), 1e-10f) + bb;
            op[(size_t)r * 256 + n * 16] = v0;                 // row kg*4+r
            const float v1 = fmaxf(acc1[n][r] * (xi1[r] * wi), 1e-10f) + bb;
            op[(size_t)(16 + r) * 256 + n * 16] = v1;          // row 16+kg*4+r
        }
    }
}

extern "C" void kernel_launch(void* const* d_in, const int* in_sizes, int n_in,
                              void* d_out, int out_size, void* d_ws, size_t ws_size,
                              hipStream_t stream) {
    const float* x = (const float*)d_in[0];
    const float* W = (const float*)d_in[1];
    const float* b = (const float*)d_in[2];
    float* out = (float*)d_out;

    hipFuncSetAttribute((const void*)ffn_cosnorm_kernel,
                        hipFuncAttributeMaxDynamicSharedMemorySize, LDS_BYTES);
    ffn_cosnorm_kernel<<<dim3(256), dim3(512), LDS_BYTES, stream>>>(x, W, b, out);
}